// Round 1
// baseline (1041.653 us; speedup 1.0000x reference)
//
#include <hip/hip_runtime.h>
#include <stdint.h>

typedef uint32_t u32;

// v_dot4_i32_i8: D = sum of signed byte products + C (CDNA VOP3P, used by CK on gfx94x+)
#if defined(__has_builtin) && __has_builtin(__builtin_amdgcn_sdot4)
#define SDOT4(a,b,c) __builtin_amdgcn_sdot4((int)(a),(int)(b),(c),false)
#else
__device__ __forceinline__ int sdot4_sw(u32 a, u32 b, int c) {
    c += (int)(int8_t)(a)       * (int)(int8_t)(b);
    c += (int)(int8_t)(a >> 8)  * (int)(int8_t)(b >> 8);
    c += (int)(int8_t)(a >> 16) * (int)(int8_t)(b >> 16);
    c += (int)(int8_t)(a >> 24) * (int)(int8_t)(b >> 24);
    return c;
}
#define SDOT4(a,b,c) sdot4_sw((a),(b),(c))
#endif

// bytes (lo..hi) starting at byte s of the pair -> compiler emits v_alignbyte_b32
__device__ __forceinline__ u32 alignb(u32 hi, u32 lo, unsigned s) {
    return (u32)((((uint64_t)hi << 32) | lo) >> (8u * s));
}
__device__ __forceinline__ u32 sgnb(float v) { return (v >= 0.f) ? 0x01u : 0xFFu; }

__device__ __forceinline__ u32 q2b(float v, float s) {
    const float r = fminf(fmaxf(rintf(__fdiv_rn(v, s)), -2.f), 1.f);
    return (u32)(uint8_t)(int8_t)(int)r;
}

// ---------------------------------------------------------------------------
// Prep: binarize+pack all weights once.
// w1p: channel-interleaved rows. [c][ky] -> 4 words: byte j (j=0..14) =
//      sign(w1[c][ci=j%3][ky][dx=j/3]), byte 15 = 0 pad.   (120 words)
// w2p: [16][6][5] rows -> 2 words (planar, unchanged)       (960 words)
// fw1p: 100x400 bytes -> 10000 words ; fw2p: 50x100 -> 1250 words
// fw3p: rows padded K 50->52 -> 10x13 words
// ---------------------------------------------------------------------------
__global__ __launch_bounds__(256) void k_prep(
    const float* __restrict__ w1, const float* __restrict__ w2,
    const float* __restrict__ fw1, const float* __restrict__ fw2,
    const float* __restrict__ fw3,
    u32* __restrict__ w1p, u32* __restrict__ w2p, u32* __restrict__ fw1p,
    u32* __restrict__ fw2p, u32* __restrict__ fw3p)
{
    const int tid = threadIdx.x;
    for (int i = tid; i < 120; i += 256) {       // i = c*20 + ky*4 + w
        const int c = i / 20, r = i % 20, ky = r / 4, w = r % 4;
        u32 v = 0;
        #pragma unroll
        for (int m = 0; m < 4; ++m) {
            const int j = 4*w + m;
            if (j < 15) {
                const int dx = j / 3, ci = j % 3;
                v |= sgnb(w1[c*75 + ci*25 + ky*5 + dx]) << (8*m);
            }
        }
        w1p[i] = v;
    }
    for (int i = tid; i < 480; i += 256) {
        const float* r = w2 + i * 5;
        w2p[i*2]   = sgnb(r[0]) | (sgnb(r[1])<<8) | (sgnb(r[2])<<16) | (sgnb(r[3])<<24);
        w2p[i*2+1] = sgnb(r[4]);
    }
    for (int i = tid; i < 10000; i += 256) {
        const float* r = fw1 + i * 4;   // flat: rows are 100 words contiguous
        fw1p[i] = sgnb(r[0]) | (sgnb(r[1])<<8) | (sgnb(r[2])<<16) | (sgnb(r[3])<<24);
    }
    for (int i = tid; i < 1250; i += 256) {
        const float* r = fw2 + i * 4;
        fw2p[i] = sgnb(r[0]) | (sgnb(r[1])<<8) | (sgnb(r[2])<<16) | (sgnb(r[3])<<24);
    }
    for (int i = tid; i < 130; i += 256) {
        const int o = i / 13, j = i % 13;
        u32 v = 0;
        #pragma unroll
        for (int m = 0; m < 4; ++m) {
            const int k = 4*j + m;
            if (k < 50) v |= sgnb(fw3[o*50 + k]) << (8*m);
        }
        fw3p[i] = v;
    }
}

// ---------------------------------------------------------------------------
// Conv1: quant_2b(x) -> conv(5x5,3->6) -> maxpool2 -> BN -> relu-quant2b
// Channel-interleaved LDS codes: row = 32 px * 3 ci bytes = 24 words, stride 28.
// Thread = (G half, sample, c, pooled_row); G wave-uniform (tid>>8).
// Each thread: 14 conv cols x 2 rows = 28 accs; 4 sdot4 per pixel per ky
// (15 useful bytes + 1 zero-pad weight byte). a1 assembled in LDS, stored
// as uint4 rows -> a1 format identical to previous version (conv2 untouched).
// ---------------------------------------------------------------------------
#define NS1 3

template<int G>
__device__ __forceinline__ void conv1_body(
    const u32* __restrict__ qs, const u32* __restrict__ wp,
    const float* __restrict__ cb, const float* __restrict__ cs,
    const float* __restrict__ cbb,
    float c1, float s_a1, int c, int py, uint8_t* __restrict__ stb)
{
    int acc0[14], acc1[14];
    #pragma unroll
    for (int t = 0; t < 14; ++t) { acc0[t] = 0; acc1[t] = 0; }

    const u32* wq = wp + c * 20;                 // [ky][4 words]
    #pragma unroll
    for (int ir = 0; ir < 6; ++ir) {
        const int r = 2 * py + ir;               // input row
        const u32* rp = qs + r * 28 + G * 8;     // G=0: words 0..15, G=1: 8..23
        u32 W[17];
        {
            const uint4 A  = *(const uint4*)(rp);
            const uint4 Bv = *(const uint4*)(rp + 4);
            const uint4 Cv = *(const uint4*)(rp + 8);
            const uint4 Dv = *(const uint4*)(rp + 12);
            W[0]=A.x;   W[1]=A.y;   W[2]=A.z;   W[3]=A.w;
            W[4]=Bv.x;  W[5]=Bv.y;  W[6]=Bv.z;  W[7]=Bv.w;
            W[8]=Cv.x;  W[9]=Cv.y;  W[10]=Cv.z; W[11]=Cv.w;
            W[12]=Dv.x; W[13]=Dv.y; W[14]=Dv.z; W[15]=Dv.w;
            W[16]=0;    // beyond-row byte only touches the zero weight pad
        }
        // byte-shifted copies; unused elements are DCE'd (all indices static)
        u32 e1[16], e2[16], e3[16];
        #pragma unroll
        for (int j = 0; j < 16; ++j) {
            e1[j] = alignb(W[j+1], W[j], 1);
            e2[j] = alignb(W[j+1], W[j], 2);
            e3[j] = alignb(W[j+1], W[j], 3);
        }
        uint4 wa, wb;
        if (ir <= 4) wa = *(const uint4*)(wq + ir * 4);        // ky = ir  (row 2py)
        if (ir >= 1) wb = *(const uint4*)(wq + (ir - 1) * 4);  // ky = ir-1(row 2py+1)
        #pragma unroll
        for (int t = 0; t < 14; ++t) {
            const int bb = 3 * (G * 14 + t);     // window start byte in row
            const int st = (bb >> 2) - 8 * G;    // local word index
            const int s  = bb & 3;               // byte shift
            #define C1DOT(ARR) \
              { if (ir <= 4) acc0[t] = SDOT4(wa.w, ARR[st+3], SDOT4(wa.z, ARR[st+2], \
                                      SDOT4(wa.y, ARR[st+1], SDOT4(wa.x, ARR[st], acc0[t])))); \
                if (ir >= 1) acc1[t] = SDOT4(wb.w, ARR[st+3], SDOT4(wb.z, ARR[st+2], \
                                      SDOT4(wb.y, ARR[st+1], SDOT4(wb.x, ARR[st], acc1[t])))); }
            if      (s == 0) C1DOT(W)
            else if (s == 1) C1DOT(e1)
            else if (s == 2) C1DOT(e2)
            else             C1DOT(e3)
            #undef C1DOT
        }
    }
    #pragma unroll
    for (int k = 0; k < 7; ++k) {
        const int m = max(max(acc0[2*k], acc0[2*k+1]), max(acc1[2*k], acc1[2*k+1]));
        const float y  = __fadd_rn(__fmul_rn((float)m, c1), cb[c]);
        const float z  = __fadd_rn(__fmul_rn(y, cs[c]), cbb[c]);
        const float t2 = __fdiv_rn(fmaxf(z, 0.f), s_a1);
        stb[G*7 + k] = (uint8_t)(int)fminf(fmaxf(rintf(t2), 0.f), 3.f);
    }
    if (G == 1) { stb[14] = 0; stb[15] = 0; }
}

__global__ __launch_bounds__(512, 4) void k_conv1(
    const float* __restrict__ x, const u32* __restrict__ w1p,
    const float* __restrict__ b1, const float* __restrict__ bn1s,
    const float* __restrict__ bn1b, const float* __restrict__ p_sin,
    const float* __restrict__ p_sw1, const float* __restrict__ p_sa1,
    uint8_t* __restrict__ a1, int B)
{
    __shared__ __align__(16) u32 q[NS1 * 896];    // [sl][row32][28 words, 24 used]
    __shared__ __align__(16) u32 wp[120];
    __shared__ __align__(16) u32 stg[NS1 * 336];  // a1 tile, global layout
    __shared__ float cb[6], cs[6], cbb[6];
    const int tid = threadIdx.x;
    const long long b0 = (long long)blockIdx.x * NS1;

    const float s_in = p_sin[0], s_a1 = p_sa1[0];
    const float c1 = __fmul_rn(s_in, p_sw1[0]);

    if (tid < 120) wp[tid] = w1p[tid];
    else if (tid >= 128 && tid < 134) {
        const int c = tid - 128;
        cb[c] = b1[c]; cs[c] = bn1s[c]; cbb[c] = bn1b[c];
    }

    // quantize + channel-interleave: one quad = 4 px * 3 ci = 3 words
    for (int i = tid; i < NS1 * 256; i += 512) {
        const int sl = i >> 8, r2 = i & 255, row = r2 >> 3, xq = r2 & 7;
        if (b0 + sl < B) {
            const float* px = x + (b0 + sl) * 3072 + row * 32 + xq * 4;
            const float4 f0 = *(const float4*)(px);
            const float4 f1 = *(const float4*)(px + 1024);
            const float4 f2 = *(const float4*)(px + 2048);
            const u32 b00 = q2b(f0.x, s_in), b01 = q2b(f1.x, s_in), b02 = q2b(f2.x, s_in);
            const u32 b10 = q2b(f0.y, s_in), b11 = q2b(f1.y, s_in), b12 = q2b(f2.y, s_in);
            const u32 b20 = q2b(f0.z, s_in), b21 = q2b(f1.z, s_in), b22 = q2b(f2.z, s_in);
            const u32 b30 = q2b(f0.w, s_in), b31 = q2b(f1.w, s_in), b32 = q2b(f2.w, s_in);
            u32* qp = q + sl * 896 + row * 28 + xq * 3;
            qp[0] = b00 | (b01 << 8) | (b02 << 16) | (b10 << 24);
            qp[1] = b11 | (b12 << 8) | (b20 << 16) | (b21 << 24);
            qp[2] = b22 | (b30 << 8) | (b31 << 16) | (b32 << 24);
        }
    }
    __syncthreads();

    const int G = tid >> 8, idx = tid & 255;     // G wave-uniform: no divergence
    if (idx < 252) {
        const int sl = idx / 84, rem = idx % 84, py = rem / 6, c = rem % 6;
        if (b0 + sl < B) {
            uint8_t* stb = (uint8_t*)stg + ((sl * 6 + c) * 14 + py) * 16;
            if (G == 0) conv1_body<0>(q + sl*896, wp, cb, cs, cbb, c1, s_a1, c, py, stb);
            else        conv1_body<1>(q + sl*896, wp, cb, cs, cbb, c1, s_a1, c, py, stb);
        }
    }
    __syncthreads();

    const long long nv = ((long long)B - b0) * 84;   // valid uint4 rows
    if (tid < NS1 * 84 && tid < nv)
        *(uint4*)(a1 + ((size_t)b0 * 84 + tid) * 16) = ((const uint4*)stg)[tid];
}

// ---------------------------------------------------------------------------
// Conv2: conv(5x5,6->16) on a1 codes -> maxpool2 -> BN -> relu-quant2b
// Thread = (sample, c_out, pooled_row). a2 out: [B][400] plain bytes.
// ---------------------------------------------------------------------------
#define NS2 3
__global__ __launch_bounds__(256) void k_conv2(
    const uint8_t* __restrict__ a1, const u32* __restrict__ w2p,
    const float* __restrict__ b2, const float* __restrict__ bn2s,
    const float* __restrict__ bn2b, const float* __restrict__ p_sa1,
    const float* __restrict__ p_sw2, const float* __restrict__ p_sa2,
    uint8_t* __restrict__ a2, int B)
{
    __shared__ u32 aL[NS2*336];         // [sl][ci6][row14][4 words]
    __shared__ u32 wp[960];
    __shared__ float cb[16], cs[16], cbb[16];
    const int tid = threadIdx.x;
    const long long b0 = (long long)blockIdx.x * NS2;

    const float c2 = __fmul_rn(p_sa1[0], p_sw2[0]);
    const float s_a2 = p_sa2[0];

    for (int i = tid; i < 960; i += 256) wp[i] = w2p[i];
    if (tid < 16) { cb[tid] = b2[tid]; cs[tid] = bn2s[tid]; cbb[tid] = bn2b[tid]; }

    const u32* a1w = (const u32*)a1;
    const long long wbase = b0 * 336;
    for (int i = tid; i < NS2*336; i += 256)
        if (wbase + i < (long long)B * 336) aL[i] = a1w[wbase + i];
    __syncthreads();

    if (tid < NS2*80) {
        const int sl = tid / 80, o = tid % 80, c = o / 5, py = o % 5;
        const long long b = b0 + sl;
        if (b < B) {
            int acc0[10], acc1[10];
            #pragma unroll
            for (int p = 0; p < 10; ++p) { acc0[p] = 0; acc1[p] = 0; }
            #pragma unroll
            for (int ci = 0; ci < 6; ++ci) {
                const u32* base = &aL[sl*336 + ci*56];
                const u32* wrow = &wp[(c*6 + ci) * 10];
                #pragma unroll
                for (int ir = 0; ir < 6; ++ir) {
                    const uint4 Wv = *(const uint4*)(base + (2*py + ir) * 4);
                    u32 W5[5] = {Wv.x, Wv.y, Wv.z, Wv.w, 0};
                    u32 e[14];
                    #pragma unroll
                    for (int j = 0; j < 4; ++j) {
                        e[4*j] = W5[j];
                        if (4*j+1 < 14) e[4*j+1] = alignb(W5[j+1], W5[j], 1);
                        if (4*j+2 < 14) e[4*j+2] = alignb(W5[j+1], W5[j], 2);
                        if (4*j+3 < 14) e[4*j+3] = alignb(W5[j+1], W5[j], 3);
                    }
                    if (ir <= 4) {
                        const u32 wa = wrow[ir*2], wb = wrow[ir*2+1];
                        #pragma unroll
                        for (int p = 0; p < 10; ++p)
                            acc0[p] = SDOT4(wa, e[p], SDOT4(wb, e[p+4], acc0[p]));
                    }
                    if (ir >= 1) {
                        const u32 wa = wrow[(ir-1)*2], wb = wrow[(ir-1)*2+1];
                        #pragma unroll
                        for (int p = 0; p < 10; ++p)
                            acc1[p] = SDOT4(wa, e[p], SDOT4(wb, e[p+4], acc1[p]));
                    }
                }
            }
            uint8_t* op = a2 + (size_t)b * 400 + c * 25 + py * 5;
            #pragma unroll
            for (int k = 0; k < 5; ++k) {
                const int m = max(max(acc0[2*k], acc0[2*k+1]),
                                  max(acc1[2*k], acc1[2*k+1]));
                const float y = __fadd_rn(__fmul_rn((float)m, c2), cb[c]);
                const float z = __fadd_rn(__fmul_rn(y, cs[c]), cbb[c]);
                const float t = __fdiv_rn(fmaxf(z, 0.f), s_a2);
                op[k] = (uint8_t)(int)fminf(fmaxf(rintf(t), 0.f), 3.f);
            }
        }
    }
}

// ---------------------------------------------------------------------------
// FC: fc1(100x400)+q -> fc2(50x100)+q -> fc3(10x50)+bias. 16 samples/block,
// packed-byte codes, sdot4 inner loops, weights staged once into LDS.
// ---------------------------------------------------------------------------
__global__ __launch_bounds__(256) void k_fc(
    const uint8_t* __restrict__ a2,
    const u32* __restrict__ fw1p, const float* __restrict__ fb1,
    const u32* __restrict__ fw2p, const float* __restrict__ fb2,
    const u32* __restrict__ fw3p, const float* __restrict__ fb3,
    const float* __restrict__ p_sa2, const float* __restrict__ p_sfw1,
    const float* __restrict__ p_sfw2, const float* __restrict__ p_sfw3,
    const float* __restrict__ p_sa3, const float* __restrict__ p_sa4,
    float* __restrict__ out, int B)
{
    __shared__ u32 w1L[10000];
    __shared__ u32 w2L[1250];
    __shared__ u32 w3L[130];
    __shared__ float bb1[100], bb2[52], bb3[12];
    __shared__ u32 xw[16*100];
    __shared__ u32 h1w[16*25];          // 100 bytes / sample
    __shared__ u32 h2w[16*13];          // 52 bytes / sample (pad = 0)
    const int tid = threadIdx.x;
    const long long b0 = (long long)blockIdx.x * 16;

    for (int i = tid; i < 10000; i += 256) w1L[i] = fw1p[i];
    for (int i = tid; i < 1250; i += 256) w2L[i] = fw2p[i];
    if (tid < 130) w3L[tid] = fw3p[tid];
    if (tid < 100) bb1[tid] = fb1[tid];
    else if (tid >= 128 && tid < 178) bb2[tid-128] = fb2[tid-128];
    else if (tid >= 192 && tid < 202) bb3[tid-192] = fb3[tid-192];
    else if (tid >= 224 && tid < 240) h2w[(tid-224)*13 + 12] = 0;
    const u32* a2w = (const u32*)a2;
    const long long wbase = b0 * 100;
    for (int i = tid; i < 1600; i += 256)
        if (wbase + i < (long long)B * 100) xw[i] = a2w[wbase + i];

    const float c3 = __fmul_rn(p_sa2[0], p_sfw1[0]);
    const float c4 = __fmul_rn(p_sa3[0], p_sfw2[0]);
    const float c5 = __fmul_rn(p_sa4[0], p_sfw3[0]);
    const float s_a3 = p_sa3[0], s_a4 = p_sa4[0];
    __syncthreads();

    for (int t = tid; t < 1600; t += 256) {
        const int s = t & 15, o = t >> 4;
        int T = 0;
        const u32* wr = &w1L[o*100];
        const u32* xr = &xw[s*100];
        #pragma unroll 10
        for (int j = 0; j < 100; ++j) T = SDOT4(wr[j], xr[j], T);
        const float y  = __fadd_rn(__fmul_rn((float)T, c3), bb1[o]);
        const float t2 = __fdiv_rn(fmaxf(y, 0.f), s_a3);
        ((uint8_t*)h1w)[s*100 + o] = (uint8_t)(int)fminf(fmaxf(rintf(t2), 0.f), 3.f);
    }
    __syncthreads();

    for (int t = tid; t < 800; t += 256) {
        const int s = t & 15, o = t >> 4;
        int T = 0;
        const u32* wr = &w2L[o*25];
        const u32* xr = &h1w[s*25];
        #pragma unroll
        for (int j = 0; j < 25; ++j) T = SDOT4(wr[j], xr[j], T);
        const float y  = __fadd_rn(__fmul_rn((float)T, c4), bb2[o]);
        const float t2 = __fdiv_rn(fmaxf(y, 0.f), s_a4);
        ((uint8_t*)h2w)[s*52 + o] = (uint8_t)(int)fminf(fmaxf(rintf(t2), 0.f), 3.f);
    }
    __syncthreads();

    for (int t = tid; t < 160; t += 256) {
        const int s = t & 15, o = t >> 4;
        if (b0 + s < B) {
            int T = 0;
            const u32* wr = &w3L[o*13];
            const u32* xr = &h2w[s*13];
            #pragma unroll
            for (int j = 0; j < 13; ++j) T = SDOT4(wr[j], xr[j], T);
            out[(size_t)(b0 + s)*10 + o] = __fadd_rn(__fmul_rn((float)T, c5), bb3[o]);
        }
    }
}

// ---------------------------------------------------------------------------
extern "C" void kernel_launch(void* const* d_in, const int* in_sizes, int n_in,
                              void* d_out, int out_size, void* d_ws, size_t ws_size,
                              hipStream_t stream)
{
    const float* x    = (const float*)d_in[0];
    const float* w1   = (const float*)d_in[1];
    const float* b1   = (const float*)d_in[2];
    const float* w2   = (const float*)d_in[3];
    const float* b2   = (const float*)d_in[4];
    const float* fw1  = (const float*)d_in[5];
    const float* fb1  = (const float*)d_in[6];
    const float* fw2  = (const float*)d_in[7];
    const float* fb2  = (const float*)d_in[8];
    const float* fw3  = (const float*)d_in[9];
    const float* fb3  = (const float*)d_in[10];
    const float* bn1s = (const float*)d_in[11];
    const float* bn1b = (const float*)d_in[12];
    const float* bn2s = (const float*)d_in[13];
    const float* bn2b = (const float*)d_in[14];
    const float* s_in = (const float*)d_in[15];
    const float* s_w1 = (const float*)d_in[16];
    const float* s_w2 = (const float*)d_in[17];
    const float* s_fw1= (const float*)d_in[18];
    const float* s_fw2= (const float*)d_in[19];
    const float* s_fw3= (const float*)d_in[20];
    const float* s_a1 = (const float*)d_in[21];
    const float* s_a2 = (const float*)d_in[22];
    const float* s_a3 = (const float*)d_in[23];
    const float* s_a4 = (const float*)d_in[24];

    int B = out_size / 10;
    if (B <= 0) B = 16384;

    // workspace carve (all 16B aligned)
    uint8_t* ws  = (uint8_t*)d_ws;
    uint8_t* a1  = ws;                                   // B*1344
    uint8_t* a2  = a1 + (size_t)B * 1344;                // B*400
    uint8_t* p   = a2 + (size_t)B * 400;
    u32* w1p  = (u32*)p;            p += 180 * 4;        // 720 (120 used)
    u32* w2p  = (u32*)p;            p += 960 * 4;        // 3840
    u32* fw1p = (u32*)p;            p += 10000 * 4;      // 40000
    u32* fw2p = (u32*)p;            p += 1250 * 4 + 8;   // 5008 (keep 16B align)
    u32* fw3p = (u32*)p;

    k_prep<<<1, 256, 0, stream>>>(w1, w2, fw1, fw2, fw3,
                                  w1p, w2p, fw1p, fw2p, fw3p);
    const int g1 = (B + NS1 - 1) / NS1;
    k_conv1<<<g1, 512, 0, stream>>>(x, w1p, b1, bn1s, bn1b, s_in, s_w1, s_a1, a1, B);
    const int g2 = (B + NS2 - 1) / NS2;
    k_conv2<<<g2, 256, 0, stream>>>(a1, w2p, b2, bn2s, bn2b, s_a1, s_w2, s_a2, a2, B);
    k_fc<<<(B + 15) / 16, 256, 0, stream>>>(a2, fw1p, fb1, fw2p, fb2, fw3p, fb3,
                                            s_a2, s_fw1, s_fw2, s_fw3, s_a3, s_a4,
                                            (float*)d_out, B);
}

// Round 2
// 549.860 us; speedup vs baseline: 1.8944x; 1.8944x over previous
//
#include <hip/hip_runtime.h>
#include <stdint.h>

typedef uint32_t u32;

// v_dot4_i32_i8: D = sum of signed byte products + C (CDNA VOP3P, used by CK on gfx94x+)
#if defined(__has_builtin) && __has_builtin(__builtin_amdgcn_sdot4)
#define SDOT4(a,b,c) __builtin_amdgcn_sdot4((int)(a),(int)(b),(c),false)
#else
__device__ __forceinline__ int sdot4_sw(u32 a, u32 b, int c) {
    c += (int)(int8_t)(a)       * (int)(int8_t)(b);
    c += (int)(int8_t)(a >> 8)  * (int)(int8_t)(b >> 8);
    c += (int)(int8_t)(a >> 16) * (int)(int8_t)(b >> 16);
    c += (int)(int8_t)(a >> 24) * (int)(int8_t)(b >> 24);
    return c;
}
#define SDOT4(a,b,c) sdot4_sw((a),(b),(c))
#endif

// bytes (lo..hi) starting at byte s of the pair -> compiler emits v_alignbyte_b32
__device__ __forceinline__ u32 alignb(u32 hi, u32 lo, unsigned s) {
    return (u32)((((uint64_t)hi << 32) | lo) >> (8u * s));
}
__device__ __forceinline__ u32 sgnb(float v) { return (v >= 0.f) ? 0x01u : 0xFFu; }

__device__ __forceinline__ u32 q2b(float v, float s) {
    const float r = fminf(fmaxf(rintf(__fdiv_rn(v, s)), -2.f), 1.f);
    return (u32)(uint8_t)(int8_t)(int)r;
}

// ---------------------------------------------------------------------------
// Prep: binarize+pack all weights once.
// w1p: PRE-SHIFTED channel-interleaved rows, 984 words:
//   word index = c*164 + ky*32 + s*8 + j  (j=0..4 used, rest 0).
//   byte m of word j = sign(w1[c][k%3][ky][k/3]) for k=4j+m-s in [0,15), else 0.
//   So a conv window starting at row byte bb (s=bb&3, wd=bb>>2) is
//   sum over words wd..wd+4 of sdot4(data_word, wshift_s word) -- no data shifts.
// w2p: [16][6][5] rows -> 2 words (planar, unchanged)       (960 words)
// fw1p: 100x400 bytes -> 10000 words ; fw2p: 50x100 -> 1250 words
// fw3p: rows padded K 50->52 -> 10x13 words
// ---------------------------------------------------------------------------
__global__ __launch_bounds__(256) void k_prep(
    const float* __restrict__ w1, const float* __restrict__ w2,
    const float* __restrict__ fw1, const float* __restrict__ fw2,
    const float* __restrict__ fw3,
    u32* __restrict__ w1p, u32* __restrict__ w2p, u32* __restrict__ fw1p,
    u32* __restrict__ fw2p, u32* __restrict__ fw3p)
{
    const int tid = threadIdx.x;
    for (int i = tid; i < 984; i += 256) {
        const int c = i / 164, r = i % 164;
        u32 v = 0;
        if (r < 160) {
            const int ky = r >> 5, r2 = r & 31, s = r2 >> 3, j = r2 & 7;
            if (j < 5) {
                #pragma unroll
                for (int m = 0; m < 4; ++m) {
                    const int k = 4*j + m - s;
                    if (k >= 0 && k < 15)
                        v |= sgnb(w1[c*75 + (k % 3)*25 + ky*5 + k/3]) << (8*m);
                }
            }
        }
        w1p[i] = v;
    }
    for (int i = tid; i < 480; i += 256) {
        const float* r = w2 + i * 5;
        w2p[i*2]   = sgnb(r[0]) | (sgnb(r[1])<<8) | (sgnb(r[2])<<16) | (sgnb(r[3])<<24);
        w2p[i*2+1] = sgnb(r[4]);
    }
    for (int i = tid; i < 10000; i += 256) {
        const float* r = fw1 + i * 4;   // flat: rows are 100 words contiguous
        fw1p[i] = sgnb(r[0]) | (sgnb(r[1])<<8) | (sgnb(r[2])<<16) | (sgnb(r[3])<<24);
    }
    for (int i = tid; i < 1250; i += 256) {
        const float* r = fw2 + i * 4;
        fw2p[i] = sgnb(r[0]) | (sgnb(r[1])<<8) | (sgnb(r[2])<<16) | (sgnb(r[3])<<24);
    }
    for (int i = tid; i < 130; i += 256) {
        const int o = i / 13, j = i % 13;
        u32 v = 0;
        #pragma unroll
        for (int m = 0; m < 4; ++m) {
            const int k = 4*j + m;
            if (k < 50) v |= sgnb(fw3[o*50 + k]) << (8*m);
        }
        fw3p[i] = v;
    }
}

// ---------------------------------------------------------------------------
// Conv1: quant_2b(x) -> conv(5x5,3->6) -> maxpool2 -> BN -> relu-quant2b
// Channel-interleaved LDS codes: row = 32 px * 3 ci bytes = 24 words, stride 28.
// Thread = (G half, sample, c, pooled_row); G wave-uniform (tid>>8).
// Pre-shifted weights (4 shift copies in LDS) -> inner loop is pure sdot4 on
// unshifted row words: 63 dots per 14-pixel conv row, no alignbytes, ~70 live
// regs (no spill). a1 format identical to round-0 (conv2/fc untouched).
// ---------------------------------------------------------------------------
#define NS1 3

template<int G>
__device__ __forceinline__ void conv1_body(
    const u32* __restrict__ qs, const u32* __restrict__ wcp,  // wp + c*164
    const float* __restrict__ cb, const float* __restrict__ cs,
    const float* __restrict__ cbb,
    float c1, float s_a1, int c, int py, uint8_t* __restrict__ stb)
{
    int acc0[14], acc1[14];
    #pragma unroll
    for (int t = 0; t < 14; ++t) { acc0[t] = 0; acc1[t] = 0; }

    #pragma unroll
    for (int ir = 0; ir < 6; ++ir) {
        const u32* rp = qs + (2*py + ir) * 28 + (G ? 8 : 0);
        u32 W[16];
        {
            const uint4 A  = *(const uint4*)(rp);
            const uint4 Bv = *(const uint4*)(rp + 4);
            const uint4 Cv = *(const uint4*)(rp + 8);
            const uint4 Dv = *(const uint4*)(rp + 12);
            W[0]=A.x;   W[1]=A.y;   W[2]=A.z;   W[3]=A.w;
            W[4]=Bv.x;  W[5]=Bv.y;  W[6]=Bv.z;  W[7]=Bv.w;
            W[8]=Cv.x;  W[9]=Cv.y;  W[10]=Cv.z; W[11]=Cv.w;
            W[12]=Dv.x; W[13]=Dv.y; W[14]=Dv.z; W[15]=Dv.w;
        }
        #pragma unroll
        for (int s = 0; s < 4; ++s) {
            u32 wa[5] = {0,0,0,0,0}, wb[5] = {0,0,0,0,0};
            if (ir <= 4) {                      // ky = ir   (conv row 2py)
                const u32* p = wcp + ir*32 + s*8;
                const uint4 v = *(const uint4*)p;
                wa[0]=v.x; wa[1]=v.y; wa[2]=v.z; wa[3]=v.w;
                if (s >= 2) wa[4] = p[4];
            }
            if (ir >= 1) {                      // ky = ir-1 (conv row 2py+1)
                const u32* p = wcp + (ir-1)*32 + s*8;
                const uint4 v = *(const uint4*)p;
                wb[0]=v.x; wb[1]=v.y; wb[2]=v.z; wb[3]=v.w;
                if (s >= 2) wb[4] = p[4];
            }
            #pragma unroll
            for (int t = 0; t < 14; ++t) {
                const int bb = 3 * (G * 14 + t);     // window start byte in row
                if ((bb & 3) != s) continue;         // compile-time filter
                const int wl = (bb >> 2) - (G ? 8 : 0);
                if (ir <= 4) {
                    int a = acc0[t];
                    a = SDOT4(wa[0], W[wl],   a);
                    a = SDOT4(wa[1], W[wl+1], a);
                    a = SDOT4(wa[2], W[wl+2], a);
                    a = SDOT4(wa[3], W[wl+3], a);
                    if (s >= 2) a = SDOT4(wa[4], W[wl+4], a);
                    acc0[t] = a;
                }
                if (ir >= 1) {
                    int a = acc1[t];
                    a = SDOT4(wb[0], W[wl],   a);
                    a = SDOT4(wb[1], W[wl+1], a);
                    a = SDOT4(wb[2], W[wl+2], a);
                    a = SDOT4(wb[3], W[wl+3], a);
                    if (s >= 2) a = SDOT4(wb[4], W[wl+4], a);
                    acc1[t] = a;
                }
            }
        }
    }
    #pragma unroll
    for (int k = 0; k < 7; ++k) {
        const int m = max(max(acc0[2*k], acc0[2*k+1]), max(acc1[2*k], acc1[2*k+1]));
        const float y  = __fadd_rn(__fmul_rn((float)m, c1), cb[c]);
        const float z  = __fadd_rn(__fmul_rn(y, cs[c]), cbb[c]);
        const float t2 = __fdiv_rn(fmaxf(z, 0.f), s_a1);
        stb[G*7 + k] = (uint8_t)(int)fminf(fmaxf(rintf(t2), 0.f), 3.f);
    }
    if (G == 1) { stb[14] = 0; stb[15] = 0; }
}

__global__ __launch_bounds__(512, 2) void k_conv1(
    const float* __restrict__ x, const u32* __restrict__ w1p,
    const float* __restrict__ b1, const float* __restrict__ bn1s,
    const float* __restrict__ bn1b, const float* __restrict__ p_sin,
    const float* __restrict__ p_sw1, const float* __restrict__ p_sa1,
    uint8_t* __restrict__ a1, int B)
{
    __shared__ __align__(16) u32 q[NS1 * 896];    // [sl][row32][28 words, 24 used]
    __shared__ __align__(16) u32 wp[984];         // pre-shifted weights, c*164 stride
    __shared__ __align__(16) u32 stg[NS1 * 336];  // a1 tile, global layout
    __shared__ float cb[6], cs[6], cbb[6];
    const int tid = threadIdx.x;
    const long long b0 = (long long)blockIdx.x * NS1;

    const float s_in = p_sin[0], s_a1 = p_sa1[0];
    const float c1 = __fmul_rn(s_in, p_sw1[0]);

    for (int i = tid; i < 984; i += 512) wp[i] = w1p[i];
    if (tid >= 1000 - 488 && tid < 1000 - 482) { } // (no-op spacing, keeps ranges clear)
    if (tid < 6) { cb[tid] = b1[tid]; cs[tid] = bn1s[tid]; cbb[tid] = bn1b[tid]; }

    // quantize + channel-interleave: one quad = 4 px * 3 ci = 3 words
    for (int i = tid; i < NS1 * 256; i += 512) {
        const int sl = i >> 8, r2 = i & 255, row = r2 >> 3, xq = r2 & 7;
        if (b0 + sl < B) {
            const float* px = x + (b0 + sl) * 3072 + row * 32 + xq * 4;
            const float4 f0 = *(const float4*)(px);
            const float4 f1 = *(const float4*)(px + 1024);
            const float4 f2 = *(const float4*)(px + 2048);
            const u32 b00 = q2b(f0.x, s_in), b01 = q2b(f1.x, s_in), b02 = q2b(f2.x, s_in);
            const u32 b10 = q2b(f0.y, s_in), b11 = q2b(f1.y, s_in), b12 = q2b(f2.y, s_in);
            const u32 b20 = q2b(f0.z, s_in), b21 = q2b(f1.z, s_in), b22 = q2b(f2.z, s_in);
            const u32 b30 = q2b(f0.w, s_in), b31 = q2b(f1.w, s_in), b32 = q2b(f2.w, s_in);
            u32* qp = q + sl * 896 + row * 28 + xq * 3;
            qp[0] = b00 | (b01 << 8) | (b02 << 16) | (b10 << 24);
            qp[1] = b11 | (b12 << 8) | (b20 << 16) | (b21 << 24);
            qp[2] = b22 | (b30 << 8) | (b31 << 16) | (b32 << 24);
        }
    }
    __syncthreads();

    const int G = tid >> 8, idx = tid & 255;     // G wave-uniform: no divergence
    if (idx < 252) {
        const int sl = idx / 84, rem = idx % 84, py = rem / 6, c = rem % 6;
        if (b0 + sl < B) {
            uint8_t* stb = (uint8_t*)stg + ((sl * 6 + c) * 14 + py) * 16;
            const u32* wcp = wp + c * 164;
            if (G == 0) conv1_body<0>(q + sl*896, wcp, cb, cs, cbb, c1, s_a1, c, py, stb);
            else        conv1_body<1>(q + sl*896, wcp, cb, cs, cbb, c1, s_a1, c, py, stb);
        }
    }
    __syncthreads();

    const long long nv = ((long long)B - b0) * 84;   // valid uint4 rows
    if (tid < NS1 * 84 && tid < nv)
        *(uint4*)(a1 + ((size_t)b0 * 84 + tid) * 16) = ((const uint4*)stg)[tid];
}

// ---------------------------------------------------------------------------
// Conv2: conv(5x5,6->16) on a1 codes -> maxpool2 -> BN -> relu-quant2b
// Thread = (sample, c_out, pooled_row). a2 out: [B][400] plain bytes.
// ---------------------------------------------------------------------------
#define NS2 3
__global__ __launch_bounds__(256) void k_conv2(
    const uint8_t* __restrict__ a1, const u32* __restrict__ w2p,
    const float* __restrict__ b2, const float* __restrict__ bn2s,
    const float* __restrict__ bn2b, const float* __restrict__ p_sa1,
    const float* __restrict__ p_sw2, const float* __restrict__ p_sa2,
    uint8_t* __restrict__ a2, int B)
{
    __shared__ u32 aL[NS2*336];         // [sl][ci6][row14][4 words]
    __shared__ u32 wp[960];
    __shared__ float cb[16], cs[16], cbb[16];
    const int tid = threadIdx.x;
    const long long b0 = (long long)blockIdx.x * NS2;

    const float c2 = __fmul_rn(p_sa1[0], p_sw2[0]);
    const float s_a2 = p_sa2[0];

    for (int i = tid; i < 960; i += 256) wp[i] = w2p[i];
    if (tid < 16) { cb[tid] = b2[tid]; cs[tid] = bn2s[tid]; cbb[tid] = bn2b[tid]; }

    const u32* a1w = (const u32*)a1;
    const long long wbase = b0 * 336;
    for (int i = tid; i < NS2*336; i += 256)
        if (wbase + i < (long long)B * 336) aL[i] = a1w[wbase + i];
    __syncthreads();

    if (tid < NS2*80) {
        const int sl = tid / 80, o = tid % 80, c = o / 5, py = o % 5;
        const long long b = b0 + sl;
        if (b < B) {
            int acc0[10], acc1[10];
            #pragma unroll
            for (int p = 0; p < 10; ++p) { acc0[p] = 0; acc1[p] = 0; }
            #pragma unroll
            for (int ci = 0; ci < 6; ++ci) {
                const u32* base = &aL[sl*336 + ci*56];
                const u32* wrow = &wp[(c*6 + ci) * 10];
                #pragma unroll
                for (int ir = 0; ir < 6; ++ir) {
                    const uint4 Wv = *(const uint4*)(base + (2*py + ir) * 4);
                    u32 W5[5] = {Wv.x, Wv.y, Wv.z, Wv.w, 0};
                    u32 e[14];
                    #pragma unroll
                    for (int j = 0; j < 4; ++j) {
                        e[4*j] = W5[j];
                        if (4*j+1 < 14) e[4*j+1] = alignb(W5[j+1], W5[j], 1);
                        if (4*j+2 < 14) e[4*j+2] = alignb(W5[j+1], W5[j], 2);
                        if (4*j+3 < 14) e[4*j+3] = alignb(W5[j+1], W5[j], 3);
                    }
                    if (ir <= 4) {
                        const u32 wa = wrow[ir*2], wb = wrow[ir*2+1];
                        #pragma unroll
                        for (int p = 0; p < 10; ++p)
                            acc0[p] = SDOT4(wa, e[p], SDOT4(wb, e[p+4], acc0[p]));
                    }
                    if (ir >= 1) {
                        const u32 wa = wrow[(ir-1)*2], wb = wrow[(ir-1)*2+1];
                        #pragma unroll
                        for (int p = 0; p < 10; ++p)
                            acc1[p] = SDOT4(wa, e[p], SDOT4(wb, e[p+4], acc1[p]));
                    }
                }
            }
            uint8_t* op = a2 + (size_t)b * 400 + c * 25 + py * 5;
            #pragma unroll
            for (int k = 0; k < 5; ++k) {
                const int m = max(max(acc0[2*k], acc0[2*k+1]),
                                  max(acc1[2*k], acc1[2*k+1]));
                const float y = __fadd_rn(__fmul_rn((float)m, c2), cb[c]);
                const float z = __fadd_rn(__fmul_rn(y, cs[c]), cbb[c]);
                const float t = __fdiv_rn(fmaxf(z, 0.f), s_a2);
                op[k] = (uint8_t)(int)fminf(fmaxf(rintf(t), 0.f), 3.f);
            }
        }
    }
}

// ---------------------------------------------------------------------------
// FC: fc1(100x400)+q -> fc2(50x100)+q -> fc3(10x50)+bias. 16 samples/block,
// packed-byte codes, sdot4 inner loops, weights staged once into LDS.
// ---------------------------------------------------------------------------
__global__ __launch_bounds__(256) void k_fc(
    const uint8_t* __restrict__ a2,
    const u32* __restrict__ fw1p, const float* __restrict__ fb1,
    const u32* __restrict__ fw2p, const float* __restrict__ fb2,
    const u32* __restrict__ fw3p, const float* __restrict__ fb3,
    const float* __restrict__ p_sa2, const float* __restrict__ p_sfw1,
    const float* __restrict__ p_sfw2, const float* __restrict__ p_sfw3,
    const float* __restrict__ p_sa3, const float* __restrict__ p_sa4,
    float* __restrict__ out, int B)
{
    __shared__ u32 w1L[10000];
    __shared__ u32 w2L[1250];
    __shared__ u32 w3L[130];
    __shared__ float bb1[100], bb2[52], bb3[12];
    __shared__ u32 xw[16*100];
    __shared__ u32 h1w[16*25];          // 100 bytes / sample
    __shared__ u32 h2w[16*13];          // 52 bytes / sample (pad = 0)
    const int tid = threadIdx.x;
    const long long b0 = (long long)blockIdx.x * 16;

    for (int i = tid; i < 10000; i += 256) w1L[i] = fw1p[i];
    for (int i = tid; i < 1250; i += 256) w2L[i] = fw2p[i];
    if (tid < 130) w3L[tid] = fw3p[tid];
    if (tid < 100) bb1[tid] = fb1[tid];
    else if (tid >= 128 && tid < 178) bb2[tid-128] = fb2[tid-128];
    else if (tid >= 192 && tid < 202) bb3[tid-192] = fb3[tid-192];
    else if (tid >= 224 && tid < 240) h2w[(tid-224)*13 + 12] = 0;
    const u32* a2w = (const u32*)a2;
    const long long wbase = b0 * 100;
    for (int i = tid; i < 1600; i += 256)
        if (wbase + i < (long long)B * 100) xw[i] = a2w[wbase + i];

    const float c3 = __fmul_rn(p_sa2[0], p_sfw1[0]);
    const float c4 = __fmul_rn(p_sa3[0], p_sfw2[0]);
    const float c5 = __fmul_rn(p_sa4[0], p_sfw3[0]);
    const float s_a3 = p_sa3[0], s_a4 = p_sa4[0];
    __syncthreads();

    for (int t = tid; t < 1600; t += 256) {
        const int s = t & 15, o = t >> 4;
        int T = 0;
        const u32* wr = &w1L[o*100];
        const u32* xr = &xw[s*100];
        #pragma unroll 10
        for (int j = 0; j < 100; ++j) T = SDOT4(wr[j], xr[j], T);
        const float y  = __fadd_rn(__fmul_rn((float)T, c3), bb1[o]);
        const float t2 = __fdiv_rn(fmaxf(y, 0.f), s_a3);
        ((uint8_t*)h1w)[s*100 + o] = (uint8_t)(int)fminf(fmaxf(rintf(t2), 0.f), 3.f);
    }
    __syncthreads();

    for (int t = tid; t < 800; t += 256) {
        const int s = t & 15, o = t >> 4;
        int T = 0;
        const u32* wr = &w2L[o*25];
        const u32* xr = &h1w[s*25];
        #pragma unroll
        for (int j = 0; j < 25; ++j) T = SDOT4(wr[j], xr[j], T);
        const float y  = __fadd_rn(__fmul_rn((float)T, c4), bb2[o]);
        const float t2 = __fdiv_rn(fmaxf(y, 0.f), s_a4);
        ((uint8_t*)h2w)[s*52 + o] = (uint8_t)(int)fminf(fmaxf(rintf(t2), 0.f), 3.f);
    }
    __syncthreads();

    for (int t = tid; t < 160; t += 256) {
        const int s = t & 15, o = t >> 4;
        if (b0 + s < B) {
            int T = 0;
            const u32* wr = &w3L[o*13];
            const u32* xr = &h2w[s*13];
            #pragma unroll
            for (int j = 0; j < 13; ++j) T = SDOT4(wr[j], xr[j], T);
            out[(size_t)(b0 + s)*10 + o] = __fadd_rn(__fmul_rn((float)T, c5), bb3[o]);
        }
    }
}

// ---------------------------------------------------------------------------
extern "C" void kernel_launch(void* const* d_in, const int* in_sizes, int n_in,
                              void* d_out, int out_size, void* d_ws, size_t ws_size,
                              hipStream_t stream)
{
    const float* x    = (const float*)d_in[0];
    const float* w1   = (const float*)d_in[1];
    const float* b1   = (const float*)d_in[2];
    const float* w2   = (const float*)d_in[3];
    const float* b2   = (const float*)d_in[4];
    const float* fw1  = (const float*)d_in[5];
    const float* fb1  = (const float*)d_in[6];
    const float* fw2  = (const float*)d_in[7];
    const float* fb2  = (const float*)d_in[8];
    const float* fw3  = (const float*)d_in[9];
    const float* fb3  = (const float*)d_in[10];
    const float* bn1s = (const float*)d_in[11];
    const float* bn1b = (const float*)d_in[12];
    const float* bn2s = (const float*)d_in[13];
    const float* bn2b = (const float*)d_in[14];
    const float* s_in = (const float*)d_in[15];
    const float* s_w1 = (const float*)d_in[16];
    const float* s_w2 = (const float*)d_in[17];
    const float* s_fw1= (const float*)d_in[18];
    const float* s_fw2= (const float*)d_in[19];
    const float* s_fw3= (const float*)d_in[20];
    const float* s_a1 = (const float*)d_in[21];
    const float* s_a2 = (const float*)d_in[22];
    const float* s_a3 = (const float*)d_in[23];
    const float* s_a4 = (const float*)d_in[24];

    int B = out_size / 10;
    if (B <= 0) B = 16384;

    // workspace carve (all 16B aligned)
    uint8_t* ws  = (uint8_t*)d_ws;
    uint8_t* a1  = ws;                                   // B*1344
    uint8_t* a2  = a1 + (size_t)B * 1344;                // B*400
    uint8_t* p   = a2 + (size_t)B * 400;
    u32* w1p  = (u32*)p;            p += 984 * 4;        // 3936 (pre-shifted)
    u32* w2p  = (u32*)p;            p += 960 * 4;        // 3840
    u32* fw1p = (u32*)p;            p += 10000 * 4;      // 40000
    u32* fw2p = (u32*)p;            p += 1250 * 4 + 8;   // 5008 (keep 16B align)
    u32* fw3p = (u32*)p;

    k_prep<<<1, 256, 0, stream>>>(w1, w2, fw1, fw2, fw3,
                                  w1p, w2p, fw1p, fw2p, fw3p);
    const int g1 = (B + NS1 - 1) / NS1;
    k_conv1<<<g1, 512, 0, stream>>>(x, w1p, b1, bn1s, bn1b, s_in, s_w1, s_a1, a1, B);
    const int g2 = (B + NS2 - 1) / NS2;
    k_conv2<<<g2, 256, 0, stream>>>(a1, w2p, b2, bn2s, bn2b, s_a1, s_w2, s_a2, a2, B);
    k_fc<<<(B + 15) / 16, 256, 0, stream>>>(a2, fw1p, fb1, fw2p, fb2, fw3p, fb3,
                                            s_a2, s_fw1, s_fw2, s_fw3, s_a3, s_a4,
                                            (float*)d_out, B);
}

// Round 3
// 482.411 us; speedup vs baseline: 2.1593x; 1.1398x over previous
//
#include <hip/hip_runtime.h>
#include <stdint.h>

typedef uint32_t u32;

// v_dot4_i32_i8: D = sum of signed byte products + C (CDNA VOP3P, used by CK on gfx94x+)
#if defined(__has_builtin) && __has_builtin(__builtin_amdgcn_sdot4)
#define SDOT4(a,b,c) __builtin_amdgcn_sdot4((int)(a),(int)(b),(c),false)
#else
__device__ __forceinline__ int sdot4_sw(u32 a, u32 b, int c) {
    c += (int)(int8_t)(a)       * (int)(int8_t)(b);
    c += (int)(int8_t)(a >> 8)  * (int)(int8_t)(b >> 8);
    c += (int)(int8_t)(a >> 16) * (int)(int8_t)(b >> 16);
    c += (int)(int8_t)(a >> 24) * (int)(int8_t)(b >> 24);
    return c;
}
#define SDOT4(a,b,c) sdot4_sw((a),(b),(c))
#endif

// bytes (lo..hi) starting at byte s of the pair -> compiler emits v_alignbyte_b32
__device__ __forceinline__ u32 alignb(u32 hi, u32 lo, unsigned s) {
    return (u32)((((uint64_t)hi << 32) | lo) >> (8u * s));
}
__device__ __forceinline__ u32 sgnb(float v) { return (v >= 0.f) ? 0x01u : 0xFFu; }

__device__ __forceinline__ u32 q2b(float v, float s) {
    const float r = fminf(fmaxf(rintf(__fdiv_rn(v, s)), -2.f), 1.f);
    return (u32)(uint8_t)(int8_t)(int)r;
}

// ---------------------------------------------------------------------------
// Prep: binarize+pack all weights once.
// w1p: 4-byte-per-tap channel-interleaved: word idx = c*25 + ky*5 + dx,
//      bytes = [sign(w1[c][0][ky][dx]), sign(w1[c][1][ky][dx]),
//               sign(w1[c][2][ky][dx]), 0].                      (150 words)
// w2p: [16][6][5] rows -> 2 words (planar, unchanged)            (960 words)
// fw1p: 100x400 bytes -> 10000 words ; fw2p: 50x100 -> 1250 words
// fw3p: rows padded K 50->52 -> 10x13 words
// ---------------------------------------------------------------------------
__global__ __launch_bounds__(256) void k_prep(
    const float* __restrict__ w1, const float* __restrict__ w2,
    const float* __restrict__ fw1, const float* __restrict__ fw2,
    const float* __restrict__ fw3,
    u32* __restrict__ w1p, u32* __restrict__ w2p, u32* __restrict__ fw1p,
    u32* __restrict__ fw2p, u32* __restrict__ fw3p)
{
    const int tid = threadIdx.x;
    for (int i = tid; i < 150; i += 256) {       // i = c*25 + ky*5 + dx
        const int c = i / 25, r = i % 25, ky = r / 5, dx = r % 5;
        w1p[i] = sgnb(w1[c*75      + ky*5 + dx])
               | (sgnb(w1[c*75 + 25 + ky*5 + dx]) << 8)
               | (sgnb(w1[c*75 + 50 + ky*5 + dx]) << 16);
    }
    for (int i = tid; i < 480; i += 256) {
        const float* r = w2 + i * 5;
        w2p[i*2]   = sgnb(r[0]) | (sgnb(r[1])<<8) | (sgnb(r[2])<<16) | (sgnb(r[3])<<24);
        w2p[i*2+1] = sgnb(r[4]);
    }
    for (int i = tid; i < 10000; i += 256) {
        const float* r = fw1 + i * 4;   // flat: rows are 100 words contiguous
        fw1p[i] = sgnb(r[0]) | (sgnb(r[1])<<8) | (sgnb(r[2])<<16) | (sgnb(r[3])<<24);
    }
    for (int i = tid; i < 1250; i += 256) {
        const float* r = fw2 + i * 4;
        fw2p[i] = sgnb(r[0]) | (sgnb(r[1])<<8) | (sgnb(r[2])<<16) | (sgnb(r[3])<<24);
    }
    for (int i = tid; i < 130; i += 256) {
        const int o = i / 13, j = i % 13;
        u32 v = 0;
        #pragma unroll
        for (int m = 0; m < 4; ++m) {
            const int k = 4*j + m;
            if (k < 50) v |= sgnb(fw3[o*50 + k]) << (8*m);
        }
        fw3p[i] = v;
    }
}

// ---------------------------------------------------------------------------
// Conv1: quant_2b(x) -> conv(5x5,3->6) -> maxpool2 -> BN -> relu-quant2b
// 4-byte-per-pixel LDS codes: row = 32 px * 4 B = 32 words, stride 36
// (16B-aligned, not 0 mod 32 banks). Every 5x5 window is word-aligned:
// 5 sdot4 per (pixel,ky), NO alignbytes, ONE weight copy (25 words in regs).
// Thread = (sample, c, pooled_row), 256-thread block (round-0 shape).
// 28 conv cols processed in 2 passes of 14 -> 28 accs live (VGPR-resident).
// a1 format identical to round-0 (conv2/fc untouched).
// ---------------------------------------------------------------------------
#define NS1 3
__global__ __launch_bounds__(256, 4) void k_conv1(
    const float* __restrict__ x, const u32* __restrict__ w1p,
    const float* __restrict__ b1, const float* __restrict__ bn1s,
    const float* __restrict__ bn1b, const float* __restrict__ p_sin,
    const float* __restrict__ p_sw1, const float* __restrict__ p_sa1,
    uint8_t* __restrict__ a1, int B)
{
    __shared__ __align__(16) u32 q[NS1 * 1152];   // [sl][row32][36 words, 32 used]
    __shared__ __align__(16) u32 wL[152];         // [c][ky][dx], c*25+ky*5+dx
    __shared__ __align__(16) u32 stg[NS1 * 336];  // a1 tile, global layout
    __shared__ float cb[6], cs[6], cbb[6];
    const int tid = threadIdx.x;
    const long long b0 = (long long)blockIdx.x * NS1;

    const float s_in = p_sin[0], s_a1 = p_sa1[0];
    const float c1 = __fmul_rn(s_in, p_sw1[0]);

    if (tid < 150) wL[tid] = w1p[tid];
    else if (tid >= 160 && tid < 166) {
        const int c = tid - 160;
        cb[c] = b1[c]; cs[c] = bn1s[c]; cbb[c] = bn1b[c];
    }

    // quantize + 4B/px interleave: one float4-triple (4 px, 3 ch) -> 4 words
    for (int i = tid; i < NS1 * 256; i += 256) {
        const int sl = i >> 8, r2 = i & 255, row = r2 >> 3, xq = r2 & 7;
        if (b0 + sl < B) {
            const float* px = x + (b0 + sl) * 3072 + row * 32 + xq * 4;
            const float4 f0 = *(const float4*)(px);
            const float4 f1 = *(const float4*)(px + 1024);
            const float4 f2 = *(const float4*)(px + 2048);
            const u32 p0 = q2b(f0.x, s_in) | (q2b(f1.x, s_in) << 8) | (q2b(f2.x, s_in) << 16);
            const u32 p1 = q2b(f0.y, s_in) | (q2b(f1.y, s_in) << 8) | (q2b(f2.y, s_in) << 16);
            const u32 p2 = q2b(f0.z, s_in) | (q2b(f1.z, s_in) << 8) | (q2b(f2.z, s_in) << 16);
            const u32 p3 = q2b(f0.w, s_in) | (q2b(f1.w, s_in) << 8) | (q2b(f2.w, s_in) << 16);
            *(uint4*)(q + sl * 1152 + row * 36 + xq * 4) = make_uint4(p0, p1, p2, p3);
        }
    }
    __syncthreads();

    if (tid < NS1 * 84) {
        const int sl = tid / 84, rem = tid % 84, py = rem / 6, c = rem % 6;
        if (b0 + sl < B) {
            // 25 weight words -> registers (static indices only)
            u32 wk[5][5];
            {
                const u32* wb_ = wL + c * 25;
                #pragma unroll
                for (int ky = 0; ky < 5; ++ky)
                    #pragma unroll
                    for (int d = 0; d < 5; ++d) wk[ky][d] = wb_[ky*5 + d];
            }
            u32 ow[4] = {0, 0, 0, 0};
            #pragma unroll
            for (int g = 0; g < 2; ++g) {         // conv cols g*14 .. g*14+13
                int acc0[14], acc1[14];
                #pragma unroll
                for (int t = 0; t < 14; ++t) { acc0[t] = 0; acc1[t] = 0; }
                #pragma unroll
                for (int ir = 0; ir < 6; ++ir) {
                    const u32* rp = q + sl*1152 + (2*py + ir)*36 + g*12;
                    u32 W[20];
                    {
                        const uint4 A  = *(const uint4*)(rp);
                        const uint4 Bv = *(const uint4*)(rp + 4);
                        const uint4 Cv = *(const uint4*)(rp + 8);
                        const uint4 Dv = *(const uint4*)(rp + 12);
                        const uint4 Ev = *(const uint4*)(rp + 16);
                        W[0]=A.x;   W[1]=A.y;   W[2]=A.z;   W[3]=A.w;
                        W[4]=Bv.x;  W[5]=Bv.y;  W[6]=Bv.z;  W[7]=Bv.w;
                        W[8]=Cv.x;  W[9]=Cv.y;  W[10]=Cv.z; W[11]=Cv.w;
                        W[12]=Dv.x; W[13]=Dv.y; W[14]=Dv.z; W[15]=Dv.w;
                        W[16]=Ev.x; W[17]=Ev.y; W[18]=Ev.z; W[19]=Ev.w;
                    }
                    #pragma unroll
                    for (int t = 0; t < 14; ++t) {
                        const int wl = t + 2*g;   // local word idx of window start
                        if (ir <= 4) {            // ky = ir   (conv row 2py)
                            int a = acc0[t];
                            a = SDOT4(wk[ir][0], W[wl],   a);
                            a = SDOT4(wk[ir][1], W[wl+1], a);
                            a = SDOT4(wk[ir][2], W[wl+2], a);
                            a = SDOT4(wk[ir][3], W[wl+3], a);
                            a = SDOT4(wk[ir][4], W[wl+4], a);
                            acc0[t] = a;
                        }
                        if (ir >= 1) {            // ky = ir-1 (conv row 2py+1)
                            int a = acc1[t];
                            a = SDOT4(wk[ir-1][0], W[wl],   a);
                            a = SDOT4(wk[ir-1][1], W[wl+1], a);
                            a = SDOT4(wk[ir-1][2], W[wl+2], a);
                            a = SDOT4(wk[ir-1][3], W[wl+3], a);
                            a = SDOT4(wk[ir-1][4], W[wl+4], a);
                            acc1[t] = a;
                        }
                    }
                }
                #pragma unroll
                for (int k = 0; k < 7; ++k) {
                    const int m = max(max(acc0[2*k], acc0[2*k+1]),
                                      max(acc1[2*k], acc1[2*k+1]));
                    const float y  = __fadd_rn(__fmul_rn((float)m, c1), cb[c]);
                    const float z  = __fadd_rn(__fmul_rn(y, cs[c]), cbb[c]);
                    const float t2 = __fdiv_rn(fmaxf(z, 0.f), s_a1);
                    const int code = (int)fminf(fmaxf(rintf(t2), 0.f), 3.f);
                    const int kk = g*7 + k;
                    ow[kk >> 2] |= (u32)code << (8 * (kk & 3));
                }
            }
            *(uint4*)(stg + ((sl*6 + c)*14 + py) * 4) =
                make_uint4(ow[0], ow[1], ow[2], ow[3]);
        }
    }
    __syncthreads();

    const long long nv = ((long long)B - b0) * 84;   // valid uint4 rows
    if (tid < NS1 * 84 && tid < nv)
        *(uint4*)(a1 + ((size_t)b0 * 84 + tid) * 16) = ((const uint4*)stg)[tid];
}

// ---------------------------------------------------------------------------
// Conv2: conv(5x5,6->16) on a1 codes -> maxpool2 -> BN -> relu-quant2b
// Thread = (sample, c_out, pooled_row). a2 out: [B][400] plain bytes.
// ---------------------------------------------------------------------------
#define NS2 3
__global__ __launch_bounds__(256) void k_conv2(
    const uint8_t* __restrict__ a1, const u32* __restrict__ w2p,
    const float* __restrict__ b2, const float* __restrict__ bn2s,
    const float* __restrict__ bn2b, const float* __restrict__ p_sa1,
    const float* __restrict__ p_sw2, const float* __restrict__ p_sa2,
    uint8_t* __restrict__ a2, int B)
{
    __shared__ u32 aL[NS2*336];         // [sl][ci6][row14][4 words]
    __shared__ u32 wp[960];
    __shared__ float cb[16], cs[16], cbb[16];
    const int tid = threadIdx.x;
    const long long b0 = (long long)blockIdx.x * NS2;

    const float c2 = __fmul_rn(p_sa1[0], p_sw2[0]);
    const float s_a2 = p_sa2[0];

    for (int i = tid; i < 960; i += 256) wp[i] = w2p[i];
    if (tid < 16) { cb[tid] = b2[tid]; cs[tid] = bn2s[tid]; cbb[tid] = bn2b[tid]; }

    const u32* a1w = (const u32*)a1;
    const long long wbase = b0 * 336;
    for (int i = tid; i < NS2*336; i += 256)
        if (wbase + i < (long long)B * 336) aL[i] = a1w[wbase + i];
    __syncthreads();

    if (tid < NS2*80) {
        const int sl = tid / 80, o = tid % 80, c = o / 5, py = o % 5;
        const long long b = b0 + sl;
        if (b < B) {
            int acc0[10], acc1[10];
            #pragma unroll
            for (int p = 0; p < 10; ++p) { acc0[p] = 0; acc1[p] = 0; }
            #pragma unroll
            for (int ci = 0; ci < 6; ++ci) {
                const u32* base = &aL[sl*336 + ci*56];
                const u32* wrow = &wp[(c*6 + ci) * 10];
                #pragma unroll
                for (int ir = 0; ir < 6; ++ir) {
                    const uint4 Wv = *(const uint4*)(base + (2*py + ir) * 4);
                    u32 W5[5] = {Wv.x, Wv.y, Wv.z, Wv.w, 0};
                    u32 e[14];
                    #pragma unroll
                    for (int j = 0; j < 4; ++j) {
                        e[4*j] = W5[j];
                        if (4*j+1 < 14) e[4*j+1] = alignb(W5[j+1], W5[j], 1);
                        if (4*j+2 < 14) e[4*j+2] = alignb(W5[j+1], W5[j], 2);
                        if (4*j+3 < 14) e[4*j+3] = alignb(W5[j+1], W5[j], 3);
                    }
                    if (ir <= 4) {
                        const u32 wa = wrow[ir*2], wb = wrow[ir*2+1];
                        #pragma unroll
                        for (int p = 0; p < 10; ++p)
                            acc0[p] = SDOT4(wa, e[p], SDOT4(wb, e[p+4], acc0[p]));
                    }
                    if (ir >= 1) {
                        const u32 wa = wrow[(ir-1)*2], wb = wrow[(ir-1)*2+1];
                        #pragma unroll
                        for (int p = 0; p < 10; ++p)
                            acc1[p] = SDOT4(wa, e[p], SDOT4(wb, e[p+4], acc1[p]));
                    }
                }
            }
            uint8_t* op = a2 + (size_t)b * 400 + c * 25 + py * 5;
            #pragma unroll
            for (int k = 0; k < 5; ++k) {
                const int m = max(max(acc0[2*k], acc0[2*k+1]),
                                  max(acc1[2*k], acc1[2*k+1]));
                const float y = __fadd_rn(__fmul_rn((float)m, c2), cb[c]);
                const float z = __fadd_rn(__fmul_rn(y, cs[c]), cbb[c]);
                const float t = __fdiv_rn(fmaxf(z, 0.f), s_a2);
                op[k] = (uint8_t)(int)fminf(fmaxf(rintf(t), 0.f), 3.f);
            }
        }
    }
}

// ---------------------------------------------------------------------------
// FC: fc1(100x400)+q -> fc2(50x100)+q -> fc3(10x50)+bias. 16 samples/block,
// packed-byte codes, sdot4 inner loops, weights staged once into LDS.
// ---------------------------------------------------------------------------
__global__ __launch_bounds__(256) void k_fc(
    const uint8_t* __restrict__ a2,
    const u32* __restrict__ fw1p, const float* __restrict__ fb1,
    const u32* __restrict__ fw2p, const float* __restrict__ fb2,
    const u32* __restrict__ fw3p, const float* __restrict__ fb3,
    const float* __restrict__ p_sa2, const float* __restrict__ p_sfw1,
    const float* __restrict__ p_sfw2, const float* __restrict__ p_sfw3,
    const float* __restrict__ p_sa3, const float* __restrict__ p_sa4,
    float* __restrict__ out, int B)
{
    __shared__ u32 w1L[10000];
    __shared__ u32 w2L[1250];
    __shared__ u32 w3L[130];
    __shared__ float bb1[100], bb2[52], bb3[12];
    __shared__ u32 xw[16*100];
    __shared__ u32 h1w[16*25];          // 100 bytes / sample
    __shared__ u32 h2w[16*13];          // 52 bytes / sample (pad = 0)
    const int tid = threadIdx.x;
    const long long b0 = (long long)blockIdx.x * 16;

    for (int i = tid; i < 10000; i += 256) w1L[i] = fw1p[i];
    for (int i = tid; i < 1250; i += 256) w2L[i] = fw2p[i];
    if (tid < 130) w3L[tid] = fw3p[tid];
    if (tid < 100) bb1[tid] = fb1[tid];
    else if (tid >= 128 && tid < 178) bb2[tid-128] = fb2[tid-128];
    else if (tid >= 192 && tid < 202) bb3[tid-192] = fb3[tid-192];
    else if (tid >= 224 && tid < 240) h2w[(tid-224)*13 + 12] = 0;
    const u32* a2w = (const u32*)a2;
    const long long wbase = b0 * 100;
    for (int i = tid; i < 1600; i += 256)
        if (wbase + i < (long long)B * 100) xw[i] = a2w[wbase + i];

    const float c3 = __fmul_rn(p_sa2[0], p_sfw1[0]);
    const float c4 = __fmul_rn(p_sa3[0], p_sfw2[0]);
    const float c5 = __fmul_rn(p_sa4[0], p_sfw3[0]);
    const float s_a3 = p_sa3[0], s_a4 = p_sa4[0];
    __syncthreads();

    for (int t = tid; t < 1600; t += 256) {
        const int s = t & 15, o = t >> 4;
        int T = 0;
        const u32* wr = &w1L[o*100];
        const u32* xr = &xw[s*100];
        #pragma unroll 10
        for (int j = 0; j < 100; ++j) T = SDOT4(wr[j], xr[j], T);
        const float y  = __fadd_rn(__fmul_rn((float)T, c3), bb1[o]);
        const float t2 = __fdiv_rn(fmaxf(y, 0.f), s_a3);
        ((uint8_t*)h1w)[s*100 + o] = (uint8_t)(int)fminf(fmaxf(rintf(t2), 0.f), 3.f);
    }
    __syncthreads();

    for (int t = tid; t < 800; t += 256) {
        const int s = t & 15, o = t >> 4;
        int T = 0;
        const u32* wr = &w2L[o*25];
        const u32* xr = &h1w[s*25];
        #pragma unroll
        for (int j = 0; j < 25; ++j) T = SDOT4(wr[j], xr[j], T);
        const float y  = __fadd_rn(__fmul_rn((float)T, c4), bb2[o]);
        const float t2 = __fdiv_rn(fmaxf(y, 0.f), s_a4);
        ((uint8_t*)h2w)[s*52 + o] = (uint8_t)(int)fminf(fmaxf(rintf(t2), 0.f), 3.f);
    }
    __syncthreads();

    for (int t = tid; t < 160; t += 256) {
        const int s = t & 15, o = t >> 4;
        if (b0 + s < B) {
            int T = 0;
            const u32* wr = &w3L[o*13];
            const u32* xr = &h2w[s*13];
            #pragma unroll
            for (int j = 0; j < 13; ++j) T = SDOT4(wr[j], xr[j], T);
            out[(size_t)(b0 + s)*10 + o] = __fadd_rn(__fmul_rn((float)T, c5), bb3[o]);
        }
    }
}

// ---------------------------------------------------------------------------
extern "C" void kernel_launch(void* const* d_in, const int* in_sizes, int n_in,
                              void* d_out, int out_size, void* d_ws, size_t ws_size,
                              hipStream_t stream)
{
    const float* x    = (const float*)d_in[0];
    const float* w1   = (const float*)d_in[1];
    const float* b1   = (const float*)d_in[2];
    const float* w2   = (const float*)d_in[3];
    const float* b2   = (const float*)d_in[4];
    const float* fw1  = (const float*)d_in[5];
    const float* fb1  = (const float*)d_in[6];
    const float* fw2  = (const float*)d_in[7];
    const float* fb2  = (const float*)d_in[8];
    const float* fw3  = (const float*)d_in[9];
    const float* fb3  = (const float*)d_in[10];
    const float* bn1s = (const float*)d_in[11];
    const float* bn1b = (const float*)d_in[12];
    const float* bn2s = (const float*)d_in[13];
    const float* bn2b = (const float*)d_in[14];
    const float* s_in = (const float*)d_in[15];
    const float* s_w1 = (const float*)d_in[16];
    const float* s_w2 = (const float*)d_in[17];
    const float* s_fw1= (const float*)d_in[18];
    const float* s_fw2= (const float*)d_in[19];
    const float* s_fw3= (const float*)d_in[20];
    const float* s_a1 = (const float*)d_in[21];
    const float* s_a2 = (const float*)d_in[22];
    const float* s_a3 = (const float*)d_in[23];
    const float* s_a4 = (const float*)d_in[24];

    int B = out_size / 10;
    if (B <= 0) B = 16384;

    // workspace carve (all 16B aligned)
    uint8_t* ws  = (uint8_t*)d_ws;
    uint8_t* a1  = ws;                                   // B*1344
    uint8_t* a2  = a1 + (size_t)B * 1344;                // B*400
    uint8_t* p   = a2 + (size_t)B * 400;
    u32* w1p  = (u32*)p;            p += 152 * 4;        // 608 (150 used)
    u32* w2p  = (u32*)p;            p += 960 * 4;        // 3840
    u32* fw1p = (u32*)p;            p += 10000 * 4;      // 40000
    u32* fw2p = (u32*)p;            p += 1250 * 4 + 8;   // 5008 (keep 16B align)
    u32* fw3p = (u32*)p;

    k_prep<<<1, 256, 0, stream>>>(w1, w2, fw1, fw2, fw3,
                                  w1p, w2p, fw1p, fw2p, fw3p);
    const int g1 = (B + NS1 - 1) / NS1;
    k_conv1<<<g1, 256, 0, stream>>>(x, w1p, b1, bn1s, bn1b, s_in, s_w1, s_a1, a1, B);
    const int g2 = (B + NS2 - 1) / NS2;
    k_conv2<<<g2, 256, 0, stream>>>(a1, w2p, b2, bn2s, bn2b, s_a1, s_w2, s_a2, a2, B);
    k_fc<<<(B + 15) / 16, 256, 0, stream>>>(a2, fw1p, fb1, fw2p, fb2, fw3p, fb3,
                                            s_a2, s_fw1, s_fw2, s_fw3, s_a3, s_a4,
                                            (float*)d_out, B);
}